// Round 3
// baseline (605.321 us; speedup 1.0000x reference)
//
#include <hip/hip_runtime.h>
#include <hip/hip_bf16.h>
#include <math.h>

#define DIMK   1024
#define HDIM   4096
#define NEXP   8
#define NTOK   4096
#define EPSV   1e-6f

typedef __attribute__((ext_vector_type(4))) float  f32x4;
typedef __attribute__((ext_vector_type(8))) __bf16 bf16x8;
typedef __attribute__((ext_vector_type(4))) __bf16 bf16x4;

__device__ __forceinline__ __bf16 f2bf(float f) { return (__bf16)f; }
__device__ __forceinline__ int imin(int a, int b) { return a < b ? a : b; }

__device__ __forceinline__ void gload_lds16(const void* g, void* l) {
    __builtin_amdgcn_global_load_lds(
        (const __attribute__((address_space(1))) void*)g,
        (__attribute__((address_space(3))) void*)l, 16, 0, 0);
}

// ---------------------------------------------------------------------------
// 0. init
// ---------------------------------------------------------------------------
__global__ void init_kernel(int* counts, int* cursors, float* S) {
    int t = threadIdx.x;
    if (t < NEXP) { counts[t] = 0; cursors[t] = 0; S[t] = 0.0f; }
}

// ---------------------------------------------------------------------------
// 1. gate (fused: also emits xbf = bf16(x), saving the separate cvt pass)
// ---------------------------------------------------------------------------
__global__ __launch_bounds__(256) void gate_kernel(
    const float* __restrict__ x, const float* __restrict__ wg,
    const float* __restrict__ bg,
    float* S, int* counts, float* score_top, int* texp,
    __bf16* __restrict__ xb)
{
    int n = blockIdx.x;
    int t = threadIdx.x;
    f32x4 xv = *(const f32x4*)(x + (size_t)n * DIMK + t * 4);

    // fused convert: write this thread's 4 elements as bf16
    bf16x4 xw = { f2bf(xv.x), f2bf(xv.y), f2bf(xv.z), f2bf(xv.w) };
    *(bf16x4*)(xb + (size_t)n * DIMK + t * 4) = xw;

    float p[NEXP];
#pragma unroll
    for (int e = 0; e < NEXP; e++) p[e] = 0.0f;
#pragma unroll
    for (int j = 0; j < 4; j++) {
        int d = t * 4 + j;
        f32x4 wa = *(const f32x4*)(wg + (size_t)d * NEXP);
        f32x4 wb = *(const f32x4*)(wg + (size_t)d * NEXP + 4);
#pragma unroll
        for (int e = 0; e < 4; e++) { p[e] += xv[j] * wa[e]; p[e + 4] += xv[j] * wb[e]; }
    }
#pragma unroll
    for (int e = 0; e < NEXP; e++) {
#pragma unroll
        for (int off = 32; off > 0; off >>= 1)
            p[e] += __shfl_down(p[e], off, 64);
    }
    __shared__ float red[4][NEXP];
    int lane = t & 63, wv = t >> 6;
    if (lane == 0) {
#pragma unroll
        for (int e = 0; e < NEXP; e++) red[wv][e] = p[e];
    }
    __syncthreads();
    if (t == 0) {
        float l[NEXP]; float m = -1e30f;
#pragma unroll
        for (int e = 0; e < NEXP; e++) {
            l[e] = red[0][e] + red[1][e] + red[2][e] + red[3][e] + bg[e];
            m = fmaxf(m, l[e]);
        }
        float pe[NEXP]; float s = 0.0f;
#pragma unroll
        for (int e = 0; e < NEXP; e++) { pe[e] = __expf(l[e] - m); s += pe[e]; }
        int best = 0; float bv = pe[0];
#pragma unroll
        for (int e = 1; e < NEXP; e++) if (pe[e] > bv) { bv = pe[e]; best = e; }
        float sc = bv / s;
        score_top[n] = sc;
        texp[n] = best;
        atomicAdd(&S[best], sc);
        atomicAdd(&counts[best], 1);
    }
}

// ---------------------------------------------------------------------------
// 2. finalize
// ---------------------------------------------------------------------------
__global__ void finalize_kernel(const float* S, const int* counts,
                                int* offsets, float* loss_out)
{
    if (threadIdx.x == 0 && blockIdx.x == 0) {
        int off = 0;
        float loadv[NEXP]; float tot = 0.0f;
        for (int e = 0; e < NEXP; e++) { offsets[e] = off; off += counts[e]; }
        for (int e = 0; e < NEXP; e++) {
            loadv[e] = S[e] / (S[e] + EPSV) * (float)NTOK;
            tot += loadv[e];
        }
        float imp = tot / (float)NTOK;
        float loss = 0.0f;
        for (int e = 0; e < NEXP; e++) { float d = loadv[e] - imp; loss += d * d; }
        loss_out[0] = loss / (float)NEXP;
    }
}

// ---------------------------------------------------------------------------
// 3. assign
// ---------------------------------------------------------------------------
__global__ __launch_bounds__(256) void assign_kernel(
    const int* __restrict__ texp, const float* __restrict__ score_top,
    const float* __restrict__ S, const int* __restrict__ offsets,
    int* cursors, int* perm, float* gatew)
{
    int n = blockIdx.x * 256 + threadIdx.x;
    int e = texp[n];
    int pos = atomicAdd(&cursors[e], 1);
    perm[offsets[e] + pos] = n;
    gatew[n] = score_top[n] / (S[e] + EPSV) * (float)NTOK;
}

// ---------------------------------------------------------------------------
// 3b. bias_init: out[n,:] = b2[e_n,:]*g_n (gemm2 atomically accumulates)
// ---------------------------------------------------------------------------
__global__ __launch_bounds__(256) void bias_init_kernel(
    const int* __restrict__ texp, const float* __restrict__ gatew,
    const float* __restrict__ b2, float* __restrict__ out)
{
    int n = blockIdx.x;
    int t = threadIdx.x;
    int e = texp[n];
    float g = gatew[n];
    f32x4 b = *(const f32x4*)(b2 + (size_t)e * DIMK + t * 4);
    f32x4 o = { b.x * g, b.y * g, b.z * g, b.w * g };
    *(f32x4*)(out + (size_t)n * DIMK + t * 4) = o;
}

// ---------------------------------------------------------------------------
// P2. transpose+convert: src[e][K][N] f32 -> dst[e][N][K] bf16, 64x64 tiles
// ---------------------------------------------------------------------------
__global__ __launch_bounds__(256) void transpose_kernel(
    const float* __restrict__ src, __bf16* __restrict__ dst, int K, int N)
{
    int tilesN = N >> 6;
    int per = (K >> 6) * tilesN;
    int e = blockIdx.x / per; int r = blockIdx.x % per;
    int tk = r / tilesN, tn = r % tilesN;
    const float* S = src + (size_t)e * K * N + (size_t)(tk << 6) * N + (tn << 6);
    __bf16* D = dst + (size_t)e * K * N + (size_t)(tn << 6) * K + (tk << 6);
    __shared__ __bf16 T[64 * 68];
    int t = threadIdx.x;
#pragma unroll
    for (int i = 0; i < 4; i++) {
        int ch = t + 256 * i;
        int k = ch >> 4, n4 = (ch & 15) << 2;
        f32x4 v = *(const f32x4*)(S + (size_t)k * N + n4);
#pragma unroll
        for (int j = 0; j < 4; j++) T[(n4 + j) * 68 + k] = f2bf(v[j]);
    }
    __syncthreads();
#pragma unroll
    for (int i = 0; i < 2; i++) {
        int o = t + 256 * i;
        int n = o >> 3, kc = o & 7;
        bf16x4 a = *(const bf16x4*)&T[n * 68 + kc * 8];
        bf16x4 b = *(const bf16x4*)&T[n * 68 + kc * 8 + 4];
        bf16x8 w = { a.x, a.y, a.z, a.w, b.x, b.y, b.z, b.w };
        *(bf16x8*)(D + (size_t)n * K + kc * 8) = w;
    }
}

// ===========================================================================
// 8-phase 256x256 BK=64 grouped-GEMM machinery (plain-HIP m201 template).
// Counted vmcnt ring (6 @ ph1/ph5, 8 @ ph4/ph8 -- never 0 in the loop),
// raw s_barrier, setprio around the MFMA cluster.
// Block-ID decode is XCD-aware: e = bid & 7  ->  expert e pinned to XCD e
// (round-robin bid%8 -> XCD), and all ACTIVE blocks are bids 0..255 so they
// dispatch first, one per CU, with zero empty-block churn in front.
// ===========================================================================

#define VM8 asm volatile("s_waitcnt vmcnt(8)" ::: "memory")
#define VM6 asm volatile("s_waitcnt vmcnt(6)" ::: "memory")
#define VM_NONE ((void)0)

#define STG_A(BUF, H, KT) do { \
    gload_lds16(agp[H][0] + (size_t)(KT) * 64, &As[BUF][H][(size_t)tid * 8]); \
    gload_lds16(agp[H][1] + (size_t)(KT) * 64, &As[BUF][H][(size_t)(512 + tid) * 8]); } while (0)

#define STG_B(BUF, H, KT) do { \
    gload_lds16(bgp[H][0] + (size_t)(KT) * 64, &Bs[BUF][H][(size_t)tid * 8]); \
    gload_lds16(bgp[H][1] + (size_t)(KT) * 64, &Bs[BUF][H][(size_t)(512 + tid) * 8]); } while (0)

#define PHB(BUF, MH, NH, STG, VM) { \
    bf16x8 Bf[2][2]; \
    _Pragma("unroll") \
    for (int ni_ = 0; ni_ < 2; ni_++) { \
        int rb_ = wn32 + ni_ * 16 + lr; \
        Bf[ni_][0] = *(const bf16x8*)(&Bs[BUF][NH][rb_ * 64 + (((lq) ^ (rb_ & 7)) << 3)]); \
        Bf[ni_][1] = *(const bf16x8*)(&Bs[BUF][NH][rb_ * 64 + (((4 + lq) ^ (rb_ & 7)) << 3)]); \
    } \
    STG; \
    __builtin_amdgcn_s_barrier(); \
    asm volatile("s_waitcnt lgkmcnt(0)" ::: "memory"); \
    __builtin_amdgcn_s_setprio(1); \
    _Pragma("unroll") \
    for (int ks_ = 0; ks_ < 2; ks_++) \
    _Pragma("unroll") \
    for (int mi_ = 0; mi_ < 4; mi_++) \
    _Pragma("unroll") \
    for (int ni_ = 0; ni_ < 2; ni_++) \
        acc[MH][NH][mi_][ni_] = __builtin_amdgcn_mfma_f32_16x16x32_bf16( \
            Af[mi_][ks_], Bf[ni_][ks_], acc[MH][NH][mi_][ni_], 0, 0, 0); \
    __builtin_amdgcn_s_setprio(0); \
    VM; \
    __builtin_amdgcn_s_barrier(); \
}

#define PAIR(BUF, MH, STG1, VM1, STG2, VM2) { \
    bf16x8 Af[4][2]; \
    _Pragma("unroll") \
    for (int mi_ = 0; mi_ < 4; mi_++) { \
        int ra_ = wm64 + mi_ * 16 + lr; \
        Af[mi_][0] = *(const bf16x8*)(&As[BUF][MH][ra_ * 64 + (((lq) ^ (ra_ & 7)) << 3)]); \
        Af[mi_][1] = *(const bf16x8*)(&As[BUF][MH][ra_ * 64 + (((4 + lq) ^ (ra_ & 7)) << 3)]); \
    } \
    PHB(BUF, MH, 0, STG1, VM1); \
    PHB(BUF, MH, 1, STG2, VM2); \
}

// ---------------------------------------------------------------------------
// 4. GEMM1: h = gelu(xbf[perm]·w1t^T + b1).  BM=BN=256 BK=64, 8-phase.
// ---------------------------------------------------------------------------
__global__ __launch_bounds__(512, 2) void gemm1_kernel(
    const __bf16* __restrict__ xbf, const __bf16* __restrict__ w1t,
    const float* __restrict__ b1,
    const int* __restrict__ perm, const int* __restrict__ counts,
    const int* __restrict__ offsets, __bf16* __restrict__ hbuf)
{
    int bx  = blockIdx.x;
    int e   = bx & 7;          // XCD-aware: expert -> XCD (bid % 8)
    int rem = bx >> 3;         // 0..255; actives are bids 0..255 (front-loaded)
    int mt  = rem >> 4, nt = rem & 15;
    int ce  = counts[e];
    int m0  = mt * 256;
    if (m0 >= ce) return;
    int off = offsets[e];
    int n0  = nt * 256;
    const __bf16* Bsrc = w1t + (size_t)e * DIMK * HDIM;

    __shared__ __bf16 As[2][2][128 * 64];
    __shared__ __bf16 Bs[2][2][128 * 64];

    int tid  = threadIdx.x;
    int lane = tid & 63, wid = tid >> 6;
    int wm64 = (wid >> 2) * 64;
    int wn32 = (wid & 3) * 32;
    int lr = lane & 15, lq = lane >> 4;

    const __bf16* agp[2][2];
    const __bf16* bgp[2][2];
    {
        int s0 = tid, s1 = 512 + tid;
        int r0 = s0 >> 3, g0 = (s0 & 7) ^ (r0 & 7);
        int r1 = s1 >> 3, g1 = (s1 & 7) ^ (r1 & 7);
#pragma unroll
        for (int h = 0; h < 2; h++) {
            int ri0 = imin(m0 + h * 128 + r0, ce - 1);
            int ri1 = imin(m0 + h * 128 + r1, ce - 1);
            agp[h][0] = xbf + (size_t)perm[off + ri0] * DIMK + g0 * 8;
            agp[h][1] = xbf + (size_t)perm[off + ri1] * DIMK + g1 * 8;
            bgp[h][0] = Bsrc + (size_t)(n0 + h * 128 + r0) * DIMK + g0 * 8;
            bgp[h][1] = Bsrc + (size_t)(n0 + h * 128 + r1) * DIMK + g1 * 8;
        }
    }

    f32x4 acc[2][2][4][2];
#pragma unroll
    for (int a = 0; a < 2; a++)
#pragma unroll
    for (int b = 0; b < 2; b++)
#pragma unroll
    for (int c = 0; c < 4; c++)
#pragma unroll
    for (int d = 0; d < 2; d++) acc[a][b][c][d] = (f32x4)0.0f;

    // prologue: ring-consistent issue order
    STG_A(0, 0, 0);   // A-lo(0)
    STG_B(0, 0, 0);   // B-lo(0)
    STG_A(0, 1, 0);   // A-hi(0)
    STG_B(0, 1, 0);   // B-hi(0)
    STG_A(1, 0, 1);   // A-lo(1)
    STG_B(1, 0, 1);   // B-lo(1)
    VM8;
    __builtin_amdgcn_s_barrier();

    const int NT = DIMK / 64;  // 16
    for (int kt = 0; kt < NT; kt += 2) {
        int k2 = imin(kt + 2, NT - 1);
        int k3 = imin(kt + 3, NT - 1);
        // tile kt (buf0)
        PAIR(0, 0, STG_A(1, 1, kt + 1), VM6, STG_B(1, 1, kt + 1), VM_NONE);
        PAIR(0, 1, STG_A(0, 0, k2),  VM_NONE, STG_B(0, 0, k2),    VM8);
        // tile kt+1 (buf1)
        PAIR(1, 0, STG_A(0, 1, k2),     VM6,  STG_B(0, 1, k2),    VM_NONE);
        PAIR(1, 1, STG_A(1, 0, k3),  VM_NONE, STG_B(1, 0, k3),    VM8);
    }

    const float* b1e = b1 + (size_t)e * HDIM;
#pragma unroll
    for (int Mh = 0; Mh < 2; Mh++)
#pragma unroll
    for (int mi = 0; mi < 4; mi++)
#pragma unroll
    for (int rr = 0; rr < 4; rr++) {
        int i = m0 + Mh * 128 + wm64 + mi * 16 + lq * 4 + rr;
        if (i < ce) {
            __bf16* hrow = hbuf + (size_t)(off + i) * HDIM;
#pragma unroll
            for (int Nh = 0; Nh < 2; Nh++)
#pragma unroll
            for (int ni = 0; ni < 2; ni++) {
                int j = n0 + Nh * 128 + wn32 + ni * 16 + lr;
                float v = acc[Mh][Nh][mi][ni][rr] + b1e[j];
                v = v / (1.0f + __expf(-1.702f * v));
                hrow[j] = f2bf(v);
            }
        }
    }
}

// ---------------------------------------------------------------------------
// 5. GEMM2: out[tok,:] += g*(h·w2t^T).  BM=BN=256 BK=64 split-K=4, 8-phase.
// ---------------------------------------------------------------------------
__global__ __launch_bounds__(512, 2) void gemm2_kernel(
    const __bf16* __restrict__ hbuf, const __bf16* __restrict__ w2t,
    const int* __restrict__ perm, const int* __restrict__ counts,
    const int* __restrict__ offsets, const float* __restrict__ gatew,
    float* __restrict__ out)
{
    int bx = blockIdx.x;
    int e  = bx & 7;           // XCD-aware: expert -> XCD (bid % 8)
    int inner = bx >> 3;       // 0..255; actives are bids 0..255
    int sk = inner & 3;
    int rr2 = inner >> 2;      // 0..63
    int mt = rr2 >> 2, nt = rr2 & 3;
    int ce = counts[e];
    int m0 = mt * 256;
    if (m0 >= ce) return;
    int off = offsets[e];
    int n0 = nt * 256;
    int kbeg = sk * (HDIM / 4);
    const __bf16* Bsrc = w2t + (size_t)e * HDIM * DIMK + kbeg;

    __shared__ __bf16 As[2][2][128 * 64];
    __shared__ __bf16 Bs[2][2][128 * 64];

    int tid  = threadIdx.x;
    int lane = tid & 63, wid = tid >> 6;
    int wm64 = (wid >> 2) * 64;
    int wn32 = (wid & 3) * 32;
    int lr = lane & 15, lq = lane >> 4;

    const __bf16* agp[2][2];
    const __bf16* bgp[2][2];
    {
        int s0 = tid, s1 = 512 + tid;
        int r0 = s0 >> 3, g0 = (s0 & 7) ^ (r0 & 7);
        int r1 = s1 >> 3, g1 = (s1 & 7) ^ (r1 & 7);
#pragma unroll
        for (int h = 0; h < 2; h++) {
            int ri0 = imin(m0 + h * 128 + r0, ce - 1);
            int ri1 = imin(m0 + h * 128 + r1, ce - 1);
            agp[h][0] = hbuf + (size_t)(off + ri0) * HDIM + kbeg + g0 * 8;
            agp[h][1] = hbuf + (size_t)(off + ri1) * HDIM + kbeg + g1 * 8;
            bgp[h][0] = Bsrc + (size_t)(n0 + h * 128 + r0) * HDIM + g0 * 8;
            bgp[h][1] = Bsrc + (size_t)(n0 + h * 128 + r1) * HDIM + g1 * 8;
        }
    }

    f32x4 acc[2][2][4][2];
#pragma unroll
    for (int a = 0; a < 2; a++)
#pragma unroll
    for (int b = 0; b < 2; b++)
#pragma unroll
    for (int c = 0; c < 4; c++)
#pragma unroll
    for (int d = 0; d < 2; d++) acc[a][b][c][d] = (f32x4)0.0f;

    STG_A(0, 0, 0);
    STG_B(0, 0, 0);
    STG_A(0, 1, 0);
    STG_B(0, 1, 0);
    STG_A(1, 0, 1);
    STG_B(1, 0, 1);
    VM8;
    __builtin_amdgcn_s_barrier();

    const int NT = (HDIM / 4) / 64;  // 16
    for (int kt = 0; kt < NT; kt += 2) {
        int k2 = imin(kt + 2, NT - 1);
        int k3 = imin(kt + 3, NT - 1);
        PAIR(0, 0, STG_A(1, 1, kt + 1), VM6, STG_B(1, 1, kt + 1), VM_NONE);
        PAIR(0, 1, STG_A(0, 0, k2),  VM_NONE, STG_B(0, 0, k2),    VM8);
        PAIR(1, 0, STG_A(0, 1, k2),     VM6,  STG_B(0, 1, k2),    VM_NONE);
        PAIR(1, 1, STG_A(1, 0, k3),  VM_NONE, STG_B(1, 0, k3),    VM8);
    }

#pragma unroll
    for (int Mh = 0; Mh < 2; Mh++)
#pragma unroll
    for (int mi = 0; mi < 4; mi++)
#pragma unroll
    for (int rr = 0; rr < 4; rr++) {
        int i = m0 + Mh * 128 + wm64 + mi * 16 + lq * 4 + rr;
        if (i < ce) {
            int tok = perm[off + i];
            float g = gatew[tok];
            float* orow = out + (size_t)tok * DIMK;
#pragma unroll
            for (int Nh = 0; Nh < 2; Nh++)
#pragma unroll
            for (int ni = 0; ni < 2; ni++) {
                int j = n0 + Nh * 128 + wn32 + ni * 16 + lr;
                atomicAdd(&orow[j], acc[Mh][Nh][mi][ni][rr] * g);
            }
        }
    }
}

// ---------------------------------------------------------------------------
// launch
// ---------------------------------------------------------------------------
extern "C" void kernel_launch(void* const* d_in, const int* in_sizes, int n_in,
                              void* d_out, int out_size, void* d_ws, size_t ws_size,
                              hipStream_t stream)
{
    const float* x  = (const float*)d_in[0];
    const float* wg = (const float*)d_in[1];
    const float* bg = (const float*)d_in[2];
    const float* w1 = (const float*)d_in[3];
    const float* b1 = (const float*)d_in[4];
    const float* w2 = (const float*)d_in[5];
    const float* b2 = (const float*)d_in[6];
    float* out = (float*)d_out;

    char* wsb = (char*)d_ws;
    int*   counts  = (int*)  (wsb + 0);
    int*   cursors = (int*)  (wsb + 32);
    int*   offsets = (int*)  (wsb + 64);
    float* S       = (float*)(wsb + 96);
    float* score   = (float*)(wsb + 128);
    int*   texp    = (int*)  (wsb + 16512);
    int*   perm    = (int*)  (wsb + 32896);
    float* gatew   = (float*)(wsb + 49280);
    __bf16* hbuf   = (__bf16*)(wsb + 131072);      // 33,554,432 B
    __bf16* xbf    = (__bf16*)(wsb + 33685504);    //  8,388,608 B
    __bf16* w1t    = (__bf16*)(wsb + 42074112);    // 67,108,864 B
    __bf16* w2t    = (__bf16*)(wsb + 109182976);   // 67,108,864 B  (end ~168 MB)

    init_kernel<<<1, 64, 0, stream>>>(counts, cursors, S);
    gate_kernel<<<NTOK, 256, 0, stream>>>(x, wg, bg, S, counts, score, texp, xbf);
    finalize_kernel<<<1, 64, 0, stream>>>(S, counts, offsets, out + (size_t)NTOK * DIMK);
    assign_kernel<<<NTOK / 256, 256, 0, stream>>>(texp, score, S, offsets,
                                                  cursors, perm, gatew);
    bias_init_kernel<<<NTOK, 256, 0, stream>>>(texp, gatew, b2, out);
    transpose_kernel<<<NEXP * 16 * 64, 256, 0, stream>>>(w1, w1t, DIMK, HDIM);
    transpose_kernel<<<NEXP * 64 * 16, 256, 0, stream>>>(w2, w2t, HDIM, DIMK);
    gemm1_kernel<<<NEXP * 16 * 16, 512, 0, stream>>>(xbf, w1t, b1, perm, counts,
                                                     offsets, hbuf);
    gemm2_kernel<<<NEXP * 16 * 4 * 4, 512, 0, stream>>>(hbuf, w2t, perm, counts,
                                                        offsets, gatew, out);
}

// Round 4
// 576.068 us; speedup vs baseline: 1.0508x; 1.0508x over previous
//
#include <hip/hip_runtime.h>
#include <hip/hip_bf16.h>
#include <math.h>

#define DIMK   1024
#define HDIM   4096
#define NEXP   8
#define NTOK   4096
#define EPSV   1e-6f

typedef __attribute__((ext_vector_type(4))) float  f32x4;
typedef __attribute__((ext_vector_type(8))) __bf16 bf16x8;
typedef __attribute__((ext_vector_type(4))) __bf16 bf16x4;

__device__ __forceinline__ __bf16 f2bf(float f) { return (__bf16)f; }

__device__ __forceinline__ void gload_lds16(const void* g, void* l) {
    __builtin_amdgcn_global_load_lds(
        (const __attribute__((address_space(1))) void*)g,
        (__attribute__((address_space(3))) void*)l, 16, 0, 0);
}

// ---------------------------------------------------------------------------
// 0. init
// ---------------------------------------------------------------------------
__global__ void init_kernel(int* counts, int* cursors, float* S) {
    int t = threadIdx.x;
    if (t < NEXP) { counts[t] = 0; cursors[t] = 0; S[t] = 0.0f; }
}

// ---------------------------------------------------------------------------
// 1. prep: ONE launch doing gate(+bf16 convert) and both weight
//    transpose+converts, by block range.  gate latency hides under the
//    BW-bound transposes; removes 2 launch gaps.
// ---------------------------------------------------------------------------
__device__ __forceinline__ void transpose_body(
    const float* __restrict__ src, __bf16* __restrict__ dst,
    int K, int N, int r, __bf16* T)
{
    int tilesN = N >> 6;
    int per = (K >> 6) * tilesN;
    int e = r / per; int rr = r % per;
    int tk = rr / tilesN, tn = rr % tilesN;
    const float* S = src + (size_t)e * K * N + (size_t)(tk << 6) * N + (tn << 6);
    __bf16* D = dst + (size_t)e * K * N + (size_t)(tn << 6) * K + (tk << 6);
    int t = threadIdx.x;
#pragma unroll
    for (int i = 0; i < 4; i++) {
        int ch = t + 256 * i;
        int k = ch >> 4, n4 = (ch & 15) << 2;
        f32x4 v = *(const f32x4*)(S + (size_t)k * N + n4);
#pragma unroll
        for (int j = 0; j < 4; j++) T[(n4 + j) * 68 + k] = f2bf(v[j]);
    }
    __syncthreads();
#pragma unroll
    for (int i = 0; i < 2; i++) {
        int o = t + 256 * i;
        int n = o >> 3, kc = o & 7;
        bf16x4 a = *(const bf16x4*)&T[n * 68 + kc * 8];
        bf16x4 b = *(const bf16x4*)&T[n * 68 + kc * 8 + 4];
        bf16x8 w = { a.x, a.y, a.z, a.w, b.x, b.y, b.z, b.w };
        *(bf16x8*)(D + (size_t)n * K + kc * 8) = w;
    }
}

__global__ __launch_bounds__(256) void prep_kernel(
    const float* __restrict__ x, const float* __restrict__ wg,
    const float* __restrict__ bg,
    float* S, int* counts, float* score_top, int* texp,
    __bf16* __restrict__ xb,
    const float* __restrict__ w1, __bf16* __restrict__ w1t,
    const float* __restrict__ w2, __bf16* __restrict__ w2t)
{
    __shared__ __bf16 T[64 * 68];
    __shared__ float red[4][NEXP];
    int bx = blockIdx.x;

    if (bx >= NTOK) {
        int r = bx - NTOK;
        if (r < 8192) transpose_body(w1, w1t, DIMK, HDIM, r, T);
        else          transpose_body(w2, w2t, HDIM, DIMK, r - 8192, T);
        return;
    }

    // ---- gate path (block = one token) ----
    int n = bx;
    int t = threadIdx.x;
    f32x4 xv = *(const f32x4*)(x + (size_t)n * DIMK + t * 4);

    // fused convert: write this thread's 4 elements as bf16
    bf16x4 xw = { f2bf(xv.x), f2bf(xv.y), f2bf(xv.z), f2bf(xv.w) };
    *(bf16x4*)(xb + (size_t)n * DIMK + t * 4) = xw;

    float p[NEXP];
#pragma unroll
    for (int e = 0; e < NEXP; e++) p[e] = 0.0f;
#pragma unroll
    for (int j = 0; j < 4; j++) {
        int d = t * 4 + j;
        f32x4 wa = *(const f32x4*)(wg + (size_t)d * NEXP);
        f32x4 wb = *(const f32x4*)(wg + (size_t)d * NEXP + 4);
#pragma unroll
        for (int e = 0; e < 4; e++) { p[e] += xv[j] * wa[e]; p[e + 4] += xv[j] * wb[e]; }
    }
#pragma unroll
    for (int e = 0; e < NEXP; e++) {
#pragma unroll
        for (int off = 32; off > 0; off >>= 1)
            p[e] += __shfl_down(p[e], off, 64);
    }
    int lane = t & 63, wv = t >> 6;
    if (lane == 0) {
#pragma unroll
        for (int e = 0; e < NEXP; e++) red[wv][e] = p[e];
    }
    __syncthreads();
    if (t == 0) {
        float l[NEXP]; float m = -1e30f;
#pragma unroll
        for (int e = 0; e < NEXP; e++) {
            l[e] = red[0][e] + red[1][e] + red[2][e] + red[3][e] + bg[e];
            m = fmaxf(m, l[e]);
        }
        float pe[NEXP]; float s = 0.0f;
#pragma unroll
        for (int e = 0; e < NEXP; e++) { pe[e] = __expf(l[e] - m); s += pe[e]; }
        int best = 0; float bv = pe[0];
#pragma unroll
        for (int e = 1; e < NEXP; e++) if (pe[e] > bv) { bv = pe[e]; best = e; }
        float sc = bv / s;
        score_top[n] = sc;
        texp[n] = best;
        atomicAdd(&S[best], sc);
        atomicAdd(&counts[best], 1);
    }
}

// ---------------------------------------------------------------------------
// 2. finalize
// ---------------------------------------------------------------------------
__global__ void finalize_kernel(const float* S, const int* counts,
                                int* offsets, float* loss_out)
{
    if (threadIdx.x == 0 && blockIdx.x == 0) {
        int off = 0;
        float loadv[NEXP]; float tot = 0.0f;
        for (int e = 0; e < NEXP; e++) { offsets[e] = off; off += counts[e]; }
        for (int e = 0; e < NEXP; e++) {
            loadv[e] = S[e] / (S[e] + EPSV) * (float)NTOK;
            tot += loadv[e];
        }
        float imp = tot / (float)NTOK;
        float loss = 0.0f;
        for (int e = 0; e < NEXP; e++) { float d = loadv[e] - imp; loss += d * d; }
        loss_out[0] = loss / (float)NEXP;
    }
}

// ---------------------------------------------------------------------------
// 3. assign + bias_init fused: block = one token.  thread0 claims the perm
//    slot; all threads write out[n,:] = b2[e,:]*g (gemm2 accumulates on top).
// ---------------------------------------------------------------------------
__global__ __launch_bounds__(256) void assign_bias_kernel(
    const int* __restrict__ texp, const float* __restrict__ score_top,
    const float* __restrict__ S, const int* __restrict__ offsets,
    int* cursors, int* perm, float* gatew,
    const float* __restrict__ b2, float* __restrict__ out)
{
    int n = blockIdx.x;
    int t = threadIdx.x;
    int e = texp[n];
    float g = score_top[n] / (S[e] + EPSV) * (float)NTOK;
    if (t == 0) {
        int pos = atomicAdd(&cursors[e], 1);
        perm[offsets[e] + pos] = n;
        gatew[n] = g;
    }
    f32x4 b = *(const f32x4*)(b2 + (size_t)e * DIMK + t * 4);
    f32x4 o = { b.x * g, b.y * g, b.z * g, b.w * g };
    *(f32x4*)(out + (size_t)n * DIMK + t * 4) = o;
}

// ---------------------------------------------------------------------------
// 4. GEMM1: h = gelu(xbf[perm]·w1t^T + b1). BM=BN=128 BK=64, m97 structure
//    (R0 code, measured best).  Decode: bid = mt*256 + e*32 + nt, so ALL
//    active blocks (mt<4 typ.) are bids 0..1023, front-loaded; grid-stride
//    over mt for safety if an expert ever exceeds 1024 rows.
// ---------------------------------------------------------------------------
__global__ __launch_bounds__(256) void gemm1_kernel(
    const __bf16* __restrict__ xbf, const __bf16* __restrict__ w1t,
    const float* __restrict__ b1,
    const int* __restrict__ perm, const int* __restrict__ counts,
    const int* __restrict__ offsets, __bf16* __restrict__ hbuf)
{
    int bx  = blockIdx.x;
    int sub = bx & 255;
    int e   = sub >> 5, nt = sub & 31;
    int ce  = counts[e];
    int off = offsets[e];
    int n0  = nt * 128;
    const __bf16* Bsrc = w1t + (size_t)e * DIMK * HDIM + (size_t)n0 * DIMK;

    __shared__ __bf16 As[128 * 64];
    __shared__ __bf16 Bs[128 * 64];

    int t = threadIdx.x;
    int lane = t & 63, wv = t >> 6;
    int wm = (wv >> 1) * 64, wn = (wv & 1) * 64;
    int lr = lane & 15, lq = lane >> 4;

    __bf16 *al[4], *bl[4];
#pragma unroll
    for (int c = 0; c < 4; c++) {
        int s = c * 256 + t;
        al[c] = As + s * 8;
        bl[c] = Bs + s * 8;
    }

    for (int mt = bx >> 8; mt * 128 < ce; mt += 8) {
        int m0 = mt * 128;

        const __bf16* ag[4]; const __bf16* bg[4];
#pragma unroll
        for (int c = 0; c < 4; c++) {
            int s = c * 256 + t;
            int row = s >> 3, pc = s & 7;
            int gc = pc ^ (row & 7);
            int ri = m0 + row; if (ri >= ce) ri = ce - 1;
            ag[c] = xbf + (size_t)perm[off + ri] * DIMK + gc * 8;
            bg[c] = Bsrc + (size_t)row * DIMK + gc * 8;
        }

        f32x4 acc[4][4];
#pragma unroll
        for (int mi = 0; mi < 4; mi++)
#pragma unroll
            for (int ni = 0; ni < 4; ni++) acc[mi][ni] = (f32x4)0.0f;

        for (int k0 = 0; k0 < DIMK; k0 += 64) {
#pragma unroll
            for (int c = 0; c < 4; c++) gload_lds16(ag[c], al[c]);
#pragma unroll
            for (int c = 0; c < 4; c++) gload_lds16(bg[c], bl[c]);
            __syncthreads();
#pragma unroll
            for (int ks = 0; ks < 2; ks++) {
                bf16x8 af[4], bfr[4];
#pragma unroll
                for (int i = 0; i < 4; i++) {
                    int ra = wm + i * 16 + lr;
                    af[i]  = *(const bf16x8*)(As + ra * 64 + (((ks * 4 + lq) ^ (ra & 7)) << 3));
                    int rb = wn + i * 16 + lr;
                    bfr[i] = *(const bf16x8*)(Bs + rb * 64 + (((ks * 4 + lq) ^ (rb & 7)) << 3));
                }
#pragma unroll
                for (int mi = 0; mi < 4; mi++)
#pragma unroll
                    for (int ni = 0; ni < 4; ni++)
                        acc[mi][ni] = __builtin_amdgcn_mfma_f32_16x16x32_bf16(
                            af[mi], bfr[ni], acc[mi][ni], 0, 0, 0);
            }
            __syncthreads();
#pragma unroll
            for (int c = 0; c < 4; c++) { ag[c] += 64; bg[c] += 64; }
        }

        const float* b1e = b1 + (size_t)e * HDIM;
#pragma unroll
        for (int mi = 0; mi < 4; mi++) {
#pragma unroll
            for (int rr = 0; rr < 4; rr++) {
                int i = m0 + wm + mi * 16 + lq * 4 + rr;
                if (i < ce) {
                    __bf16* hrow = hbuf + (size_t)(off + i) * HDIM;
#pragma unroll
                    for (int ni = 0; ni < 4; ni++) {
                        int j = n0 + wn + ni * 16 + lr;
                        float v = acc[mi][ni][rr] + b1e[j];
                        v = v / (1.0f + __expf(-1.702f * v));
                        hrow[j] = f2bf(v);
                    }
                }
            }
        }
    }
}

// ---------------------------------------------------------------------------
// 5. GEMM2: out[tok,:] += g*(h·w2t^T). BM=BN=128 BK=64 split-K=2, atomics.
//    R0 structure; decode bid = mt*128 + e*16 + nt*2 + sk (actives front).
// ---------------------------------------------------------------------------
__global__ __launch_bounds__(256) void gemm2_kernel(
    const __bf16* __restrict__ hbuf, const __bf16* __restrict__ w2t,
    const int* __restrict__ perm, const int* __restrict__ counts,
    const int* __restrict__ offsets, const float* __restrict__ gatew,
    float* __restrict__ out)
{
    int bx  = blockIdx.x;
    int sub = bx & 127;
    int e   = sub >> 4;
    int nt  = (sub >> 1) & 7;
    int sk  = sub & 1;
    int ce  = counts[e];
    int off = offsets[e];
    int n0  = nt * 128;
    int kbeg = sk * (HDIM / 2);
    const __bf16* Bsrc = w2t + (size_t)e * HDIM * DIMK + (size_t)n0 * HDIM;

    __shared__ __bf16 As[128 * 64];
    __shared__ __bf16 Bs[128 * 64];

    int t = threadIdx.x;
    int lane = t & 63, wv = t >> 6;
    int wm = (wv >> 1) * 64, wn = (wv & 1) * 64;
    int lr = lane & 15, lq = lane >> 4;

    __bf16 *al[4], *bl[4];
#pragma unroll
    for (int c = 0; c < 4; c++) {
        int s = c * 256 + t;
        al[c] = As + s * 8;
        bl[c] = Bs + s * 8;
    }

    for (int mt = bx >> 7; mt * 128 < ce; mt += 8) {
        int m0 = mt * 128;

        const __bf16* ag[4]; const __bf16* bg[4];
#pragma unroll
        for (int c = 0; c < 4; c++) {
            int s = c * 256 + t;
            int row = s >> 3, pc = s & 7;
            int gc = pc ^ (row & 7);
            int ri = m0 + row; if (ri >= ce) ri = ce - 1;
            ag[c] = hbuf + (size_t)(off + ri) * HDIM + kbeg + gc * 8;
            bg[c] = Bsrc + (size_t)row * HDIM + kbeg + gc * 8;
        }

        f32x4 acc[4][4];
#pragma unroll
        for (int mi = 0; mi < 4; mi++)
#pragma unroll
            for (int ni = 0; ni < 4; ni++) acc[mi][ni] = (f32x4)0.0f;

        for (int k0 = 0; k0 < HDIM / 2; k0 += 64) {
#pragma unroll
            for (int c = 0; c < 4; c++) gload_lds16(ag[c], al[c]);
#pragma unroll
            for (int c = 0; c < 4; c++) gload_lds16(bg[c], bl[c]);
            __syncthreads();
#pragma unroll
            for (int ks = 0; ks < 2; ks++) {
                bf16x8 af[4], bfr[4];
#pragma unroll
                for (int i = 0; i < 4; i++) {
                    int ra = wm + i * 16 + lr;
                    af[i]  = *(const bf16x8*)(As + ra * 64 + (((ks * 4 + lq) ^ (ra & 7)) << 3));
                    int rb = wn + i * 16 + lr;
                    bfr[i] = *(const bf16x8*)(Bs + rb * 64 + (((ks * 4 + lq) ^ (rb & 7)) << 3));
                }
#pragma unroll
                for (int mi = 0; mi < 4; mi++)
#pragma unroll
                    for (int ni = 0; ni < 4; ni++)
                        acc[mi][ni] = __builtin_amdgcn_mfma_f32_16x16x32_bf16(
                            af[mi], bfr[ni], acc[mi][ni], 0, 0, 0);
            }
            __syncthreads();
#pragma unroll
            for (int c = 0; c < 4; c++) { ag[c] += 64; bg[c] += 64; }
        }

#pragma unroll
        for (int mi = 0; mi < 4; mi++) {
#pragma unroll
            for (int rr = 0; rr < 4; rr++) {
                int i = m0 + wm + mi * 16 + lq * 4 + rr;
                if (i < ce) {
                    int tok = perm[off + i];
                    float g = gatew[tok];
                    float* orow = out + (size_t)tok * DIMK;
#pragma unroll
                    for (int ni = 0; ni < 4; ni++) {
                        int j = n0 + wn + ni * 16 + lr;
                        atomicAdd(&orow[j], acc[mi][ni][rr] * g);
                    }
                }
            }
        }
    }
}

// ---------------------------------------------------------------------------
// launch
// ---------------------------------------------------------------------------
extern "C" void kernel_launch(void* const* d_in, const int* in_sizes, int n_in,
                              void* d_out, int out_size, void* d_ws, size_t ws_size,
                              hipStream_t stream)
{
    const float* x  = (const float*)d_in[0];
    const float* wg = (const float*)d_in[1];
    const float* bg = (const float*)d_in[2];
    const float* w1 = (const float*)d_in[3];
    const float* b1 = (const float*)d_in[4];
    const float* w2 = (const float*)d_in[5];
    const float* b2 = (const float*)d_in[6];
    float* out = (float*)d_out;

    char* wsb = (char*)d_ws;
    int*   counts  = (int*)  (wsb + 0);
    int*   cursors = (int*)  (wsb + 32);
    int*   offsets = (int*)  (wsb + 64);
    float* S       = (float*)(wsb + 96);
    float* score   = (float*)(wsb + 128);
    int*   texp    = (int*)  (wsb + 16512);
    int*   perm    = (int*)  (wsb + 32896);
    float* gatew   = (float*)(wsb + 49280);
    __bf16* hbuf   = (__bf16*)(wsb + 131072);      // 33,554,432 B
    __bf16* xbf    = (__bf16*)(wsb + 33685504);    //  8,388,608 B
    __bf16* w1t    = (__bf16*)(wsb + 42074112);    // 67,108,864 B
    __bf16* w2t    = (__bf16*)(wsb + 109182976);   // 67,108,864 B  (end ~168 MB)

    init_kernel<<<1, 64, 0, stream>>>(counts, cursors, S);
    prep_kernel<<<NTOK + 8192 + 8192, 256, 0, stream>>>(
        x, wg, bg, S, counts, score, texp, xbf, w1, w1t, w2, w2t);
    finalize_kernel<<<1, 64, 0, stream>>>(S, counts, offsets, out + (size_t)NTOK * DIMK);
    assign_bias_kernel<<<NTOK, 256, 0, stream>>>(texp, score, S, offsets,
                                                 cursors, perm, gatew, b2, out);
    gemm1_kernel<<<2048, 256, 0, stream>>>(xbf, w1t, b1, perm, counts,
                                           offsets, hbuf);
    gemm2_kernel<<<1024, 256, 0, stream>>>(hbuf, w2t, perm, counts,
                                           offsets, gatew, out);
}